// Round 2
// baseline (3516.197 us; speedup 1.0000x reference)
//
#include <hip/hip_runtime.h>
#include <hip/hip_bf16.h>

#define H64 64

// ---------- typed load/store helpers (ws storage type XT) ----------
__device__ __forceinline__ float xload(const float* p, long i) { return p[i]; }
__device__ __forceinline__ float xload(const __hip_bfloat16* p, long i) { return __bfloat162float(p[i]); }
__device__ __forceinline__ void xstore(float* p, long i, float v) { p[i] = v; }
__device__ __forceinline__ void xstore(__hip_bfloat16* p, long i, float v) { p[i] = __float2bfloat16(v); }

__device__ __forceinline__ float wload(const void* p, long i, bool f32) {
    return f32 ? ((const float*)p)[i]
               : __bfloat162float(((const __hip_bfloat16*)p)[i]);
}

// ---------- runtime format detection ----------
// flags[0] != 0  -> edge indices are int32 (odd words nonzero); ==0 -> int64
// flags[1] > 64  -> x tensors are f32; else bf16
// flags[2] > 64  -> weight tensors are f32; else bf16
__global__ void detect_k(const unsigned int* __restrict__ eiw, int nwords,
                         const unsigned short* __restrict__ xw,
                         const unsigned short* __restrict__ ww,
                         unsigned int* __restrict__ flags) {
    int t = threadIdx.x;
    unsigned int acc = 0;
    for (int i = 1 + 2 * t; i < nwords; i += 512) acc |= eiw[i];
    if (acc) atomicOr(&flags[0], acc);
    unsigned int cx = 0, cw = 0;
    for (int i = t; i < 8192; i += 256) {
        unsigned short w = xw[i];
        unsigned int e = (w >> 7) & 0xFF;
        if ((w & 0x7FFF) && (e == 0xFF || e < 0x40)) cx++;
        w = ww[i];
        e = (w >> 7) & 0xFF;
        if ((w & 0x7FFF) && (e == 0xFF || e < 0x40)) cw++;
    }
    if (cx) atomicAdd(&flags[1], cx);
    if (cw) atomicAdd(&flags[2], cw);
}

// ---------- convert harness x input -> ws storage ----------
template <typename XT>
__global__ void conv_in(const void* __restrict__ src, XT* __restrict__ dst,
                        long n, const unsigned int* __restrict__ flags) {
    bool xf32 = flags[1] > 64;
    long i = (long)blockIdx.x * blockDim.x + threadIdx.x;
    long stride = (long)gridDim.x * blockDim.x;
    for (; i < n; i += stride) {
        float v = xf32 ? ((const float*)src)[i]
                       : __bfloat162float(((const __hip_bfloat16*)src)[i]);
        xstore(dst, i, v);
    }
}

// ---------- in-degree counts (edge structure is layer-invariant) ----------
__global__ void scatter_cnt(const int* __restrict__ ei, int E,
                            const unsigned int* __restrict__ flags,
                            float* __restrict__ cnt) {
    bool is64 = (flags[0] == 0u);
    int e = blockIdx.x * blockDim.x + threadIdx.x;
    if (e >= E) return;
    int dst = is64 ? ei[2 * E + 2 * e] : ei[E + e];
    atomicAdd(&cnt[dst], 1.0f);
}

// ---------- feature scatter: sum[dst,:] += x[src,:] (one wave per edge) ----------
template <typename XT>
__global__ void scatter_feat(const XT* __restrict__ xsrc,
                             const int* __restrict__ ei, int E,
                             const unsigned int* __restrict__ flags,
                             float* __restrict__ sum) {
    bool is64 = (flags[0] == 0u);
    int lane = threadIdx.x & 63;
    int e = blockIdx.x * 4 + (threadIdx.x >> 6);
    if (e >= E) return;
    int src, dst;
    if (is64) { src = ei[2 * e]; dst = ei[2 * E + 2 * e]; }
    else      { src = ei[e];     dst = ei[E + e]; }
    atomicAdd(&sum[(long)dst * H64 + lane], xload(xsrc, (long)src * H64 + lane));
}

// ---------- fused per-relation update ----------
// xnext[d,:] += (sum[d,:]/max(cnt,1)) @ Wl + bl + xdst[d,:] @ Wr
// 64 dst rows x 64 cols per block; two K=64 phases share ~33 KB LDS.
template <typename XT>
__global__ __launch_bounds__(256) void rel_update(
    const float* __restrict__ sum, const float* __restrict__ cnt,
    const XT* __restrict__ xdst, XT* __restrict__ xnext,
    const void* __restrict__ Wl_b, const void* __restrict__ Wr_b,
    const void* __restrict__ bl_b, long wOff, long bOff,
    const unsigned int* __restrict__ flags, int n_dst) {
    __shared__ float WS[64 * 64];   // 16 KB  [k][j]
    __shared__ float AT[64 * 68];   // 17 KB  [k][r]
    bool wf32 = flags[2] > 64;
    int t = threadIdx.x;
    int d0 = blockIdx.x * 64;
    int r = t & 63, kc = t >> 6, d = d0 + r;
    bool valid = d < n_dst;
    float rc = valid ? 1.0f / fmaxf(cnt[d], 1.0f) : 0.f;
    int tx = t & 15, ty = t >> 4;
    float acc[4][4] = {{0.f}};

    // phase 0: agg @ Wl
    for (int i = t; i < 4096; i += 256) WS[i] = wload(Wl_b, wOff + i, wf32);
    #pragma unroll
    for (int kk = 0; kk < 16; ++kk) {
        int k = kc * 16 + kk;
        AT[k * 68 + r] = valid ? sum[(long)d * H64 + k] * rc : 0.f;
    }
    __syncthreads();
    #pragma unroll 8
    for (int k = 0; k < 64; ++k) {
        float4 a = *(const float4*)&AT[k * 68 + ty * 4];
        float4 w = *(const float4*)&WS[k * 64 + tx * 4];
        acc[0][0] += a.x * w.x; acc[0][1] += a.x * w.y; acc[0][2] += a.x * w.z; acc[0][3] += a.x * w.w;
        acc[1][0] += a.y * w.x; acc[1][1] += a.y * w.y; acc[1][2] += a.y * w.z; acc[1][3] += a.y * w.w;
        acc[2][0] += a.z * w.x; acc[2][1] += a.z * w.y; acc[2][2] += a.z * w.z; acc[2][3] += a.z * w.w;
        acc[3][0] += a.w * w.x; acc[3][1] += a.w * w.y; acc[3][2] += a.w * w.z; acc[3][3] += a.w * w.w;
    }
    __syncthreads();

    // phase 1: xdst @ Wr
    for (int i = t; i < 4096; i += 256) WS[i] = wload(Wr_b, wOff + i, wf32);
    #pragma unroll
    for (int kk = 0; kk < 16; ++kk) {
        int k = kc * 16 + kk;
        AT[k * 68 + r] = valid ? xload(xdst, (long)d * H64 + k) : 0.f;
    }
    __syncthreads();
    #pragma unroll 8
    for (int k = 0; k < 64; ++k) {
        float4 a = *(const float4*)&AT[k * 68 + ty * 4];
        float4 w = *(const float4*)&WS[k * 64 + tx * 4];
        acc[0][0] += a.x * w.x; acc[0][1] += a.x * w.y; acc[0][2] += a.x * w.z; acc[0][3] += a.x * w.w;
        acc[1][0] += a.y * w.x; acc[1][1] += a.y * w.y; acc[1][2] += a.y * w.z; acc[1][3] += a.y * w.w;
        acc[2][0] += a.z * w.x; acc[2][1] += a.z * w.y; acc[2][2] += a.z * w.z; acc[2][3] += a.z * w.w;
        acc[3][0] += a.w * w.x; acc[3][1] += a.w * w.y; acc[3][2] += a.w * w.z; acc[3][3] += a.w * w.w;
    }

    float blv[4];
    #pragma unroll
    for (int j = 0; j < 4; ++j) blv[j] = wload(bl_b, bOff + tx * 4 + j, wf32);
    #pragma unroll
    for (int i = 0; i < 4; ++i) {
        int dd = d0 + ty * 4 + i;
        if (dd < n_dst) {
            #pragma unroll
            for (int j = 0; j < 4; ++j) {
                long idx = (long)dd * H64 + tx * 4 + j;
                xstore(xnext, idx, xload(xnext, idx) + acc[i][j] + blv[j]);
            }
        }
    }
}

// ---------- relu in place ----------
template <typename XT>
__global__ void relu_k(XT* __restrict__ x, long n) {
    long i = (long)blockIdx.x * blockDim.x + threadIdx.x;
    long stride = (long)gridDim.x * blockDim.x;
    for (; i < n; i += stride) xstore(x, i, fmaxf(xload(x, i), 0.f));
}

// ---------- head: softplus(x@projW+projb) @ outW + outb ----------
template <typename XT>
__global__ __launch_bounds__(256) void head_k(
    const XT* __restrict__ xc,
    const void* __restrict__ projW, const void* __restrict__ projb,
    const void* __restrict__ outW, const void* __restrict__ outb,
    void* __restrict__ out, const unsigned int* __restrict__ flags, int n) {
    __shared__ float PW[64 * 64];
    __shared__ float PB[64], OW[64];
    __shared__ float ROW[4][64];
    bool wf32 = flags[2] > 64;
    bool of32 = flags[1] > 64;   // output dtype follows input dtype
    int t = threadIdx.x;
    for (int i = t; i < 4096; i += 256) PW[i] = wload(projW, i, wf32);
    if (t < 64) { PB[t] = wload(projb, t, wf32); OW[t] = wload(outW, t, wf32); }
    int wid = t >> 6, lane = t & 63;
    int d = blockIdx.x * 4 + wid;
    ROW[wid][lane] = (d < n) ? xload(xc, (long)d * H64 + lane) : 0.f;
    __syncthreads();
    if (d < n) {
        float s = PB[lane];
        #pragma unroll 8
        for (int k = 0; k < 64; ++k) s += ROW[wid][k] * PW[k * 64 + lane];
        float sp = fmaxf(s, 0.f) + log1pf(expf(-fabsf(s)));
        float c = sp * OW[lane];
        #pragma unroll
        for (int off = 32; off; off >>= 1) c += __shfl_down(c, off, 64);
        if (lane == 0) {
            float rv = c + wload(outb, 0, wf32);
            if (of32) ((float*)out)[d] = rv;
            else ((__hip_bfloat16*)out)[d] = __float2bfloat16(rv);
        }
    }
}

// ---------- host-side pipeline (templated on ws storage type) ----------
template <typename XT>
static void run_pipeline(void* const* d_in, char* base, unsigned int* flags,
                         const long* rows, const long* rowoff, long NX,
                         const long* Es, const long* cntoff, long cntN, long SUMN,
                         void* d_out, hipStream_t stream) {
    static const int rel_st[9] = {0, 0, 0, 1, 1, 2, 0, 1, 2};
    static const int rel_dt[9] = {0, 1, 2, 1, 2, 2, 3, 3, 3};

    size_t xbytes = (size_t)NX * sizeof(XT);
    XT* xA = (XT*)base;
    XT* xB = (XT*)(base + xbytes);
    float* sum = (float*)(base + 2 * xbytes);
    float* cnt = sum + SUMN;

    for (int t = 0; t < 4; ++t) {
        long n = rows[t] * H64;
        int blocks = (int)((n + 255) / 256); if (blocks > 8192) blocks = 8192;
        conv_in<XT><<<blocks, 256, 0, stream>>>(d_in[t], xA + rowoff[t] * H64, n, flags);
    }

    hipMemsetAsync(cnt, 0, (size_t)cntN * sizeof(float), stream);
    for (int r = 0; r < 9; ++r)
        scatter_cnt<<<(int)((Es[r] + 255) / 256), 256, 0, stream>>>(
            (const int*)d_in[11 + r], (int)Es[r], flags, cnt + cntoff[r]);

    XT* xc = xA;
    XT* xn = xB;
    for (int l = 0; l < 3; ++l) {
        hipMemsetAsync(xn, 0, xbytes, stream);
        for (int r = 0; r < 9; ++r) {
            int st = rel_st[r], dt = rel_dt[r];
            long nd = rows[dt];
            hipMemsetAsync(sum, 0, (size_t)nd * H64 * sizeof(float), stream);
            scatter_feat<XT><<<(int)((Es[r] + 3) / 4), 256, 0, stream>>>(
                xc + rowoff[st] * H64, (const int*)d_in[11 + r], (int)Es[r], flags, sum);
            rel_update<XT><<<(int)((nd + 63) / 64), 256, 0, stream>>>(
                sum, cnt + cntoff[r], xc + rowoff[dt] * H64, xn + rowoff[dt] * H64,
                d_in[4], d_in[6], d_in[5],
                (long)(l * 9 + r) * 4096, (long)(l * 9 + r) * 64, flags, (int)nd);
        }
        relu_k<XT><<<8192, 256, 0, stream>>>(xn, NX);
        XT* tmp = xc; xc = xn; xn = tmp;
    }

    head_k<XT><<<(int)((rows[3] + 3) / 4), 256, 0, stream>>>(
        xc + rowoff[3] * H64, d_in[7], d_in[8], d_in[9], d_in[10], d_out, flags, (int)rows[3]);
}

extern "C" void kernel_launch(void* const* d_in, const int* in_sizes, int n_in,
                              void* d_out, int out_size, void* d_ws, size_t ws_size,
                              hipStream_t stream) {
    static const int rel_dt[9] = {0, 1, 2, 1, 2, 2, 3, 3, 3};

    long rows[4], rowoff[4], total = 0;
    for (int t = 0; t < 4; ++t) { rows[t] = in_sizes[t] / H64; rowoff[t] = total; total += rows[t]; }
    long NX = total * H64;
    long Es[9];
    for (int r = 0; r < 9; ++r) Es[r] = (long)in_sizes[11 + r] / 2;
    long cntoff[9], cntN = 0;
    for (int r = 0; r < 9; ++r) { cntoff[r] = cntN; cntN += rows[rel_dt[r]]; }
    long maxdst = 0;
    for (int r = 0; r < 9; ++r) if (rows[rel_dt[r]] > maxdst) maxdst = rows[rel_dt[r]];
    long SUMN = maxdst * H64;

    unsigned int* flags = (unsigned int*)d_ws;
    char* base = (char*)d_ws + 64;
    size_t needA = 64 + (size_t)NX * 4 * 2 + (size_t)(SUMN + cntN) * 4;

    hipMemsetAsync(d_ws, 0, 64, stream);
    int nwords = 16384;
    if (in_sizes[11] < nwords) nwords = in_sizes[11];
    detect_k<<<1, 256, 0, stream>>>((const unsigned int*)d_in[11], nwords,
                                    (const unsigned short*)d_in[0],
                                    (const unsigned short*)d_in[4], flags);

    if (ws_size >= needA)
        run_pipeline<float>(d_in, base, flags, rows, rowoff, NX, Es, cntoff, cntN, SUMN, d_out, stream);
    else
        run_pipeline<__hip_bfloat16>(d_in, base, flags, rows, rowoff, NX, Es, cntoff, cntN, SUMN, d_out, stream);
}

// Round 3
// 1840.709 us; speedup vs baseline: 1.9102x; 1.9102x over previous
//
#include <hip/hip_runtime.h>
#include <hip/hip_bf16.h>

#define H64 64

// ---------- typed load/store helpers (ws storage type XT) ----------
__device__ __forceinline__ float xload(const float* p, long i) { return p[i]; }
__device__ __forceinline__ float xload(const __hip_bfloat16* p, long i) { return __bfloat162float(p[i]); }
__device__ __forceinline__ void xstore(float* p, long i, float v) { p[i] = v; }
__device__ __forceinline__ void xstore(__hip_bfloat16* p, long i, float v) { p[i] = __float2bfloat16(v); }

__device__ __forceinline__ float wload(const void* p, long i, bool f32) {
    return f32 ? ((const float*)p)[i]
               : __bfloat162float(((const __hip_bfloat16*)p)[i]);
}

// ---------- runtime format detection ----------
// flags[0] != 0 -> edge indices int32 (odd words nonzero); ==0 -> int64
// flags[1] > 64 -> x tensors f32; else bf16.  flags[2] > 64 -> weights f32.
__global__ void detect_k(const unsigned int* __restrict__ eiw, int nwords,
                         const unsigned short* __restrict__ xw,
                         const unsigned short* __restrict__ ww,
                         unsigned int* __restrict__ flags) {
    int t = threadIdx.x;
    unsigned int acc = 0;
    for (int i = 1 + 2 * t; i < nwords; i += 512) acc |= eiw[i];
    if (acc) atomicOr(&flags[0], acc);
    unsigned int cx = 0, cw = 0;
    for (int i = t; i < 8192; i += 256) {
        unsigned short w = xw[i];
        unsigned int e = (w >> 7) & 0xFF;
        if ((w & 0x7FFF) && (e == 0xFF || e < 0x40)) cx++;
        w = ww[i];
        e = (w >> 7) & 0xFF;
        if ((w & 0x7FFF) && (e == 0xFF || e < 0x40)) cw++;
    }
    if (cx) atomicAdd(&flags[1], cx);
    if (cw) atomicAdd(&flags[2], cw);
}

// ---------- convert harness x input -> ws storage ----------
template <typename XT>
__global__ void conv_in(const void* __restrict__ src, XT* __restrict__ dst,
                        long n, const unsigned int* __restrict__ flags) {
    bool xf32 = flags[1] > 64;
    long i = (long)blockIdx.x * blockDim.x + threadIdx.x;
    long stride = (long)gridDim.x * blockDim.x;
    for (; i < n; i += stride) {
        float v = xf32 ? ((const float*)src)[i]
                       : __bfloat162float(((const __hip_bfloat16*)src)[i]);
        xstore(dst, i, v);
    }
}

// ---------- Wr/bl pre-sum per (layer, dst type) ----------
__global__ void wsum_k(const void* __restrict__ Wr, const void* __restrict__ bl,
                       const unsigned int* __restrict__ flags,
                       float* __restrict__ Wsum, float* __restrict__ blsum) {
    const int rel_dt[9] = {0, 1, 2, 1, 2, 2, 3, 3, 3};
    bool wf32 = flags[2] > 64;
    int l = blockIdx.x >> 2, dt = blockIdx.x & 3;
    for (int i = threadIdx.x; i < 4096; i += 256) {
        float s = 0.f;
        for (int r = 0; r < 9; ++r)
            if (rel_dt[r] == dt) s += wload(Wr, (long)(l * 9 + r) * 4096 + i, wf32);
        Wsum[(long)blockIdx.x * 4096 + i] = s;
    }
    if (threadIdx.x < 64) {
        float s = 0.f;
        for (int r = 0; r < 9; ++r)
            if (rel_dt[r] == dt) s += wload(bl, (long)(l * 9 + r) * 64 + threadIdx.x, wf32);
        blsum[blockIdx.x * 64 + threadIdx.x] = s;
    }
}

// ---------- CSR build ----------
__global__ void scatter_cnt_i(const int* __restrict__ ei, int E,
                              const unsigned int* __restrict__ flags,
                              int* __restrict__ cnt) {
    bool is64 = (flags[0] == 0u);
    int e = blockIdx.x * blockDim.x + threadIdx.x;
    if (e >= E) return;
    int dst = is64 ? ei[2 * E + 2 * e] : ei[E + e];
    atomicAdd(&cnt[dst], 1);
}

__global__ void scan_bsum(const int* __restrict__ cnt, int n, int* __restrict__ bsums) {
    __shared__ int red[256];
    int i = blockIdx.x * 256 + threadIdx.x;
    red[threadIdx.x] = (i < n) ? cnt[i] : 0;
    __syncthreads();
    for (int s = 128; s; s >>= 1) {
        if (threadIdx.x < s) red[threadIdx.x] += red[threadIdx.x + s];
        __syncthreads();
    }
    if (threadIdx.x == 0) bsums[blockIdx.x] = red[0];
}

__global__ void scan_excl_single(int* __restrict__ data, int n) {
    __shared__ int buf[1024];
    __shared__ int carry_s;
    if (threadIdx.x == 0) carry_s = 0;
    __syncthreads();
    for (int base = 0; base < n; base += 1024) {
        int i = base + threadIdx.x;
        int v = (i < n) ? data[i] : 0;
        buf[threadIdx.x] = v;
        __syncthreads();
        for (int off = 1; off < 1024; off <<= 1) {
            int tv = (threadIdx.x >= off) ? buf[threadIdx.x - off] : 0;
            __syncthreads();
            buf[threadIdx.x] += tv;
            __syncthreads();
        }
        int incl = buf[threadIdx.x];
        int carry = carry_s;
        if (i < n) data[i] = carry + incl - v;   // exclusive
        __syncthreads();
        if (threadIdx.x == 1023) carry_s = carry + buf[1023];
        __syncthreads();
    }
}

__global__ void scan_rowptr(const int* __restrict__ cnt, const int* __restrict__ bsums,
                            int n, int* __restrict__ row_ptr) {
    __shared__ int buf[256];
    int i = blockIdx.x * 256 + threadIdx.x;
    int v = (i < n) ? cnt[i] : 0;
    buf[threadIdx.x] = v;
    __syncthreads();
    for (int off = 1; off < 256; off <<= 1) {
        int tv = (threadIdx.x >= off) ? buf[threadIdx.x - off] : 0;
        __syncthreads();
        buf[threadIdx.x] += tv;
        __syncthreads();
    }
    int excl = buf[threadIdx.x] - v + bsums[blockIdx.x];
    if (i < n) row_ptr[i] = excl;
    if (i == n - 1) row_ptr[n] = excl + v;
}

__global__ void csr_fill(const int* __restrict__ ei, int E,
                         const unsigned int* __restrict__ flags,
                         int cntoff, int srcbase,
                         int* __restrict__ cursor, int* __restrict__ edge_src) {
    bool is64 = (flags[0] == 0u);
    int e = blockIdx.x * blockDim.x + threadIdx.x;
    if (e >= E) return;
    int src, dst;
    if (is64) { src = ei[2 * e]; dst = ei[2 * E + 2 * e]; }
    else      { src = ei[e];     dst = ei[E + e]; }
    int pos = atomicAdd(&cursor[cntoff + dst], 1);
    edge_src[pos] = srcbase + src;
}

// ---------- gather-mean: one wave per concatenated dst row ----------
template <typename XT>
__global__ void gather_mean(const XT* __restrict__ x, const int* __restrict__ edge_src,
                            const int* __restrict__ row_ptr,
                            __hip_bfloat16* __restrict__ agg, int nrows) {
    int w = blockIdx.x * 4 + (threadIdx.x >> 6);
    int lane = threadIdx.x & 63;
    if (w >= nrows) return;
    int s = row_ptr[w], t = row_ptr[w + 1];
    float acc = 0.f;
    int e = s;
    for (; e + 4 <= t; e += 4) {
        int s0 = edge_src[e], s1 = edge_src[e + 1], s2 = edge_src[e + 2], s3 = edge_src[e + 3];
        float a0 = xload(x, (long)s0 * H64 + lane);
        float a1 = xload(x, (long)s1 * H64 + lane);
        float a2 = xload(x, (long)s2 * H64 + lane);
        float a3 = xload(x, (long)s3 * H64 + lane);
        acc += (a0 + a1) + (a2 + a3);
    }
    for (; e < t; ++e) acc += xload(x, (long)edge_src[e] * H64 + lane);
    float m = (t > s) ? acc / (float)(t - s) : 0.f;
    agg[(long)w * H64 + lane] = __float2bfloat16(m);
}

// ---------- 64x64x64 GEMM micro-kernel on LDS tiles ----------
__device__ __forceinline__ void gemm64(float acc[4][4], const float* AT, const float* WS,
                                       int tx, int ty) {
    #pragma unroll 8
    for (int k = 0; k < 64; ++k) {
        float4 a = *(const float4*)&AT[k * 68 + ty * 4];
        float4 w = *(const float4*)&WS[k * 64 + tx * 4];
        acc[0][0] += a.x * w.x; acc[0][1] += a.x * w.y; acc[0][2] += a.x * w.z; acc[0][3] += a.x * w.w;
        acc[1][0] += a.y * w.x; acc[1][1] += a.y * w.y; acc[1][2] += a.y * w.z; acc[1][3] += a.y * w.w;
        acc[2][0] += a.z * w.x; acc[2][1] += a.z * w.y; acc[2][2] += a.z * w.z; acc[2][3] += a.z * w.w;
        acc[3][0] += a.w * w.x; acc[3][1] += a.w * w.y; acc[3][2] += a.w * w.z; acc[3][3] += a.w * w.w;
    }
}

// ---------- fused per-dst-type layer update (in place on x) ----------
// x[d,:] = relu( sum_p agg_p[d,:] @ Wl_p  +  x[d,:] @ Wsum  +  blsum )
template <typename XT>
__global__ __launch_bounds__(256) void fused_update(
    XT* __restrict__ x,                       // base of this dst type's rows
    const __hip_bfloat16* __restrict__ agg,   // concatenated agg base
    long aggRow0, long aggRow1, long aggRow2, // agg row offsets per relation
    long wlOff0, long wlOff1, long wlOff2,    // Wl element offsets per relation
    int R,
    const void* __restrict__ Wl_b, const unsigned int* __restrict__ flags,
    const float* __restrict__ Wsum, const float* __restrict__ blsum,
    int n_dst) {
    __shared__ float WS[4096];      // 16 KB [k][j]
    __shared__ float AT[64 * 68];   // 17 KB [k][r]
    bool wf32 = flags[2] > 64;
    int t = threadIdx.x;
    int d0 = blockIdx.x * 64;
    int r = t & 63, kc = t >> 6, d = d0 + r;
    bool valid = d < n_dst;
    int tx = t & 15, ty = t >> 4;
    float acc[4][4] = {{0.f}};
    long aggRows[3] = {aggRow0, aggRow1, aggRow2};
    long wlOffs[3] = {wlOff0, wlOff1, wlOff2};

    for (int p = 0; p < R; ++p) {
        for (int i = t; i < 4096; i += 256) WS[i] = wload(Wl_b, wlOffs[p] + i, wf32);
        const __hip_bfloat16* arow = agg + (aggRows[p] + d) * H64;
        #pragma unroll
        for (int kk = 0; kk < 16; ++kk) {
            int k = kc * 16 + kk;
            AT[k * 68 + r] = valid ? __bfloat162float(arow[k]) : 0.f;
        }
        __syncthreads();
        gemm64(acc, AT, WS, tx, ty);
        __syncthreads();
    }
    // self term
    for (int i = t; i < 4096; i += 256) WS[i] = Wsum[i];
    #pragma unroll
    for (int kk = 0; kk < 16; ++kk) {
        int k = kc * 16 + kk;
        AT[k * 68 + r] = valid ? xload(x, (long)d * H64 + k) : 0.f;
    }
    __syncthreads();
    gemm64(acc, AT, WS, tx, ty);

    float blv[4];
    #pragma unroll
    for (int j = 0; j < 4; ++j) blv[j] = blsum[tx * 4 + j];
    #pragma unroll
    for (int i = 0; i < 4; ++i) {
        int dd = d0 + ty * 4 + i;
        if (dd < n_dst) {
            #pragma unroll
            for (int j = 0; j < 4; ++j)
                xstore(x, (long)dd * H64 + tx * 4 + j, fmaxf(acc[i][j] + blv[j], 0.f));
        }
    }
}

// ---------- head: softplus(x@projW+projb) @ outW + outb ----------
template <typename XT>
__global__ __launch_bounds__(256) void head_k(
    const XT* __restrict__ xc,
    const void* __restrict__ projW, const void* __restrict__ projb,
    const void* __restrict__ outW, const void* __restrict__ outb,
    void* __restrict__ out, const unsigned int* __restrict__ flags, int n) {
    __shared__ float PW[64 * 64];
    __shared__ float PB[64], OW[64];
    __shared__ float ROW[4][64];
    bool wf32 = flags[2] > 64;
    bool of32 = flags[1] > 64;
    int t = threadIdx.x;
    for (int i = t; i < 4096; i += 256) PW[i] = wload(projW, i, wf32);
    if (t < 64) { PB[t] = wload(projb, t, wf32); OW[t] = wload(outW, t, wf32); }
    int wid = t >> 6, lane = t & 63;
    int d = blockIdx.x * 4 + wid;
    ROW[wid][lane] = (d < n) ? xload(xc, (long)d * H64 + lane) : 0.f;
    __syncthreads();
    if (d < n) {
        float s = PB[lane];
        #pragma unroll 8
        for (int k = 0; k < 64; ++k) s += ROW[wid][k] * PW[k * 64 + lane];
        float sp = fmaxf(s, 0.f) + log1pf(expf(-fabsf(s)));
        float c = sp * OW[lane];
        #pragma unroll
        for (int off = 32; off; off >>= 1) c += __shfl_down(c, off, 64);
        if (lane == 0) {
            float rv = c + wload(outb, 0, wf32);
            if (of32) ((float*)out)[d] = rv;
            else ((__hip_bfloat16*)out)[d] = __float2bfloat16(rv);
        }
    }
}

// ---------- host-side pipeline ----------
template <typename XT>
static void run_pipeline(void* const* d_in, char* wsbase, unsigned int* flags,
                         const long* rows, const long* rowoff, long NX,
                         const long* Es, const long* cntoff, long cntN, long ET,
                         void* d_out, hipStream_t stream) {
    static const int rel_st[9] = {0, 0, 0, 1, 1, 2, 0, 1, 2};
    static const int relsOf[4][3] = {{0, -1, -1}, {1, 3, -1}, {2, 4, 5}, {6, 7, 8}};
    static const int Rof[4] = {1, 2, 3, 3};

    auto align16 = [](size_t v) { return (v + 15) & ~(size_t)15; };
    size_t off = 0;
    XT* x = (XT*)(wsbase + off);                 off = align16(off + (size_t)NX * sizeof(XT));
    __hip_bfloat16* agg = (__hip_bfloat16*)(wsbase + off); off = align16(off + (size_t)cntN * H64 * 2);
    int* cnt_i = (int*)(wsbase + off);           off = align16(off + (size_t)cntN * 4);
    int* row_ptr = (int*)(wsbase + off);         off = align16(off + (size_t)(cntN + 1) * 4);
    int* cursor = (int*)(wsbase + off);          off = align16(off + (size_t)cntN * 4);
    int* edge_src = (int*)(wsbase + off);        off = align16(off + (size_t)ET * 4);
    long nb1 = (cntN + 255) / 256;
    int* bsums = (int*)(wsbase + off);           off = align16(off + (size_t)nb1 * 4);
    float* Wsum = (float*)(wsbase + off);        off = align16(off + (size_t)12 * 4096 * 4);
    float* blsum = (float*)(wsbase + off);       off = align16(off + (size_t)12 * 64 * 4);

    // x inputs -> ws
    for (int t = 0; t < 4; ++t) {
        long n = rows[t] * H64;
        int blocks = (int)((n + 255) / 256); if (blocks > 8192) blocks = 8192;
        conv_in<XT><<<blocks, 256, 0, stream>>>(d_in[t], x + rowoff[t] * H64, n, flags);
    }

    // Wr / bl pre-sums
    wsum_k<<<12, 256, 0, stream>>>(d_in[6], d_in[5], flags, Wsum, blsum);

    // CSR build (edge structure is layer-invariant)
    hipMemsetAsync(cnt_i, 0, (size_t)cntN * 4, stream);
    for (int r = 0; r < 9; ++r)
        if (Es[r] > 0)
            scatter_cnt_i<<<(int)((Es[r] + 255) / 256), 256, 0, stream>>>(
                (const int*)d_in[11 + r], (int)Es[r], flags, cnt_i + cntoff[r]);
    scan_bsum<<<(int)nb1, 256, 0, stream>>>(cnt_i, (int)cntN, bsums);
    scan_excl_single<<<1, 1024, 0, stream>>>(bsums, (int)nb1);
    scan_rowptr<<<(int)nb1, 256, 0, stream>>>(cnt_i, bsums, (int)cntN, row_ptr);
    hipMemcpyAsync(cursor, row_ptr, (size_t)cntN * 4, hipMemcpyDeviceToDevice, stream);
    for (int r = 0; r < 9; ++r)
        if (Es[r] > 0)
            csr_fill<<<(int)((Es[r] + 255) / 256), 256, 0, stream>>>(
                (const int*)d_in[11 + r], (int)Es[r], flags,
                (int)cntoff[r], (int)rowoff[rel_st[r]], cursor, edge_src);

    // layers
    for (int l = 0; l < 3; ++l) {
        gather_mean<XT><<<(int)((cntN + 3) / 4), 256, 0, stream>>>(
            x, edge_src, row_ptr, agg, (int)cntN);
        for (int dt = 0; dt < 4; ++dt) {
            int R = Rof[dt];
            long ar[3] = {0, 0, 0}, wo[3] = {0, 0, 0};
            for (int p = 0; p < R; ++p) {
                int rr = relsOf[dt][p];
                ar[p] = cntoff[rr];
                wo[p] = (long)(l * 9 + rr) * 4096;
            }
            long nd = rows[dt];
            fused_update<XT><<<(int)((nd + 63) / 64), 256, 0, stream>>>(
                x + rowoff[dt] * H64, agg, ar[0], ar[1], ar[2], wo[0], wo[1], wo[2], R,
                d_in[4], flags, Wsum + (size_t)(l * 4 + dt) * 4096,
                blsum + (size_t)(l * 4 + dt) * 64, (int)nd);
        }
    }

    head_k<XT><<<(int)((rows[3] + 3) / 4), 256, 0, stream>>>(
        x + rowoff[3] * H64, d_in[7], d_in[8], d_in[9], d_in[10], d_out, flags, (int)rows[3]);
}

extern "C" void kernel_launch(void* const* d_in, const int* in_sizes, int n_in,
                              void* d_out, int out_size, void* d_ws, size_t ws_size,
                              hipStream_t stream) {
    static const int rel_dt[9] = {0, 1, 2, 1, 2, 2, 3, 3, 3};

    long rows[4], rowoff[4], total = 0;
    for (int t = 0; t < 4; ++t) { rows[t] = in_sizes[t] / H64; rowoff[t] = total; total += rows[t]; }
    long NX = total * H64;
    long Es[9], ET = 0;
    for (int r = 0; r < 9; ++r) { Es[r] = (long)in_sizes[11 + r] / 2; ET += Es[r]; }
    long cntoff[9], cntN = 0;
    for (int r = 0; r < 9; ++r) { cntoff[r] = cntN; cntN += rows[rel_dt[r]]; }
    long nb1 = (cntN + 255) / 256;

    unsigned int* flags = (unsigned int*)d_ws;
    char* wsbase = (char*)d_ws + 64;

    // bytes needed beyond x buffer
    size_t fixed = (size_t)cntN * H64 * 2 + (size_t)cntN * 4 * 2 + (size_t)(cntN + 1) * 4 +
                   (size_t)ET * 4 + (size_t)nb1 * 4 + (size_t)12 * 4096 * 4 +
                   (size_t)12 * 64 * 4 + 256;
    size_t needF32 = 64 + (size_t)NX * 4 + fixed;

    hipMemsetAsync(d_ws, 0, 64, stream);
    int nwords = 16384;
    if (in_sizes[11] < nwords) nwords = in_sizes[11];
    detect_k<<<1, 256, 0, stream>>>((const unsigned int*)d_in[11], nwords,
                                    (const unsigned short*)d_in[0],
                                    (const unsigned short*)d_in[4], flags);

    if (ws_size >= needF32)
        run_pipeline<float>(d_in, wsbase, flags, rows, rowoff, NX, Es, cntoff, cntN, ET, d_out, stream);
    else
        run_pipeline<__hip_bfloat16>(d_in, wsbase, flags, rows, rowoff, NX, Es, cntoff, cntN, ET, d_out, stream);
}

// Round 4
// 1101.900 us; speedup vs baseline: 3.1910x; 1.6705x over previous
//
#include <hip/hip_runtime.h>
#include <hip/hip_bf16.h>

#define H64 64

typedef __bf16 bf16_t;
typedef __bf16 bf16x8 __attribute__((ext_vector_type(8)));
typedef float f32x4 __attribute__((ext_vector_type(4)));

// ---------- helpers ----------
__device__ __forceinline__ float wload(const void* p, long i, bool f32) {
    return f32 ? ((const float*)p)[i]
               : __bfloat162float(((const __hip_bfloat16*)p)[i]);
}
__device__ __forceinline__ float blo(unsigned v) { return __uint_as_float(v << 16); }
__device__ __forceinline__ float bhi(unsigned v) { return __uint_as_float(v & 0xffff0000u); }

// ---------- runtime format detection ----------
// flags[0] != 0 -> edge indices int32 (odd words nonzero); ==0 -> int64
// flags[1] > 64 -> x tensors f32; else bf16.  flags[2] > 64 -> weights f32.
__global__ void detect_k(const unsigned int* __restrict__ eiw, int nwords,
                         const unsigned short* __restrict__ xw,
                         const unsigned short* __restrict__ ww,
                         unsigned int* __restrict__ flags) {
    int t = threadIdx.x;
    unsigned int acc = 0;
    for (int i = 1 + 2 * t; i < nwords; i += 512) acc |= eiw[i];
    if (acc) atomicOr(&flags[0], acc);
    unsigned int cx = 0, cw = 0;
    for (int i = t; i < 8192; i += 256) {
        unsigned short w = xw[i];
        unsigned int e = (w >> 7) & 0xFF;
        if ((w & 0x7FFF) && (e == 0xFF || e < 0x40)) cx++;
        w = ww[i];
        e = (w >> 7) & 0xFF;
        if ((w & 0x7FFF) && (e == 0xFF || e < 0x40)) cw++;
    }
    if (cx) atomicAdd(&flags[1], cx);
    if (cw) atomicAdd(&flags[2], cw);
}

// ---------- convert harness x input -> bf16 ws storage ----------
__global__ void conv_in(const void* __restrict__ src, __hip_bfloat16* __restrict__ dst,
                        long n, const unsigned int* __restrict__ flags) {
    bool xf32 = flags[1] > 64;
    long i = (long)blockIdx.x * blockDim.x + threadIdx.x;
    long stride = (long)gridDim.x * blockDim.x;
    for (; i < n; i += stride) {
        float v = xf32 ? ((const float*)src)[i]
                       : __bfloat162float(((const __hip_bfloat16*)src)[i]);
        dst[i] = __float2bfloat16(v);
    }
}

// ---------- weight prep: bf16, transposed WT[n][k]; Wr pre-summed per (l,dt) ----------
// blockIdx.x = l*13 + p.  p<9: WT of Wl[l,p].  p in 9..12: dt=p-9, WT of sum(Wr) + blsum.
__global__ void prep_w(const void* __restrict__ Wl, const void* __restrict__ Wr,
                       const void* __restrict__ bl, const unsigned int* __restrict__ flags,
                       bf16_t* __restrict__ wt, float* __restrict__ blsum) {
    const int rel_dt[9] = {0, 1, 2, 1, 2, 2, 3, 3, 3};
    bool wf32 = flags[2] > 64;
    int l = blockIdx.x / 13, p = blockIdx.x % 13;
    bf16_t* dst = wt + (long)blockIdx.x * 4096;
    for (int i = threadIdx.x; i < 4096; i += 256) {
        int n = i >> 6, k = i & 63;
        float v;
        if (p < 9) {
            v = wload(Wl, (long)(l * 9 + p) * 4096 + k * 64 + n, wf32);
        } else {
            int dt = p - 9;
            v = 0.f;
            for (int r = 0; r < 9; ++r)
                if (rel_dt[r] == dt) v += wload(Wr, (long)(l * 9 + r) * 4096 + k * 64 + n, wf32);
        }
        __hip_bfloat16 h = __float2bfloat16(v);
        dst[i] = *(bf16_t*)&h;
    }
    if (p >= 9 && threadIdx.x < 64) {
        int dt = p - 9;
        float s = 0.f;
        for (int r = 0; r < 9; ++r)
            if (rel_dt[r] == dt) s += wload(bl, (long)(l * 9 + r) * 64 + threadIdx.x, wf32);
        blsum[(l * 4 + dt) * 64 + threadIdx.x] = s;
    }
}

// ---------- CSR build ----------
__global__ void scatter_cnt_i(const int* __restrict__ ei, int E,
                              const unsigned int* __restrict__ flags,
                              int* __restrict__ cnt) {
    bool is64 = (flags[0] == 0u);
    int e = blockIdx.x * blockDim.x + threadIdx.x;
    if (e >= E) return;
    int dst = is64 ? ei[2 * E + 2 * e] : ei[E + e];
    atomicAdd(&cnt[dst], 1);
}

__global__ void scan_bsum(const int* __restrict__ cnt, int n, int* __restrict__ bsums) {
    __shared__ int red[256];
    int i = blockIdx.x * 256 + threadIdx.x;
    red[threadIdx.x] = (i < n) ? cnt[i] : 0;
    __syncthreads();
    for (int s = 128; s; s >>= 1) {
        if (threadIdx.x < s) red[threadIdx.x] += red[threadIdx.x + s];
        __syncthreads();
    }
    if (threadIdx.x == 0) bsums[blockIdx.x] = red[0];
}

__global__ void scan_excl_single(int* __restrict__ data, int n) {
    __shared__ int buf[1024];
    __shared__ int carry_s;
    if (threadIdx.x == 0) carry_s = 0;
    __syncthreads();
    for (int base = 0; base < n; base += 1024) {
        int i = base + threadIdx.x;
        int v = (i < n) ? data[i] : 0;
        buf[threadIdx.x] = v;
        __syncthreads();
        for (int off = 1; off < 1024; off <<= 1) {
            int tv = (threadIdx.x >= off) ? buf[threadIdx.x - off] : 0;
            __syncthreads();
            buf[threadIdx.x] += tv;
            __syncthreads();
        }
        int incl = buf[threadIdx.x];
        int carry = carry_s;
        if (i < n) data[i] = carry + incl - v;
        __syncthreads();
        if (threadIdx.x == 1023) carry_s = carry + buf[1023];
        __syncthreads();
    }
}

__global__ void scan_rowptr(const int* __restrict__ cnt, const int* __restrict__ bsums,
                            int n, int* __restrict__ row_ptr) {
    __shared__ int buf[256];
    int i = blockIdx.x * 256 + threadIdx.x;
    int v = (i < n) ? cnt[i] : 0;
    buf[threadIdx.x] = v;
    __syncthreads();
    for (int off = 1; off < 256; off <<= 1) {
        int tv = (threadIdx.x >= off) ? buf[threadIdx.x - off] : 0;
        __syncthreads();
        buf[threadIdx.x] += tv;
        __syncthreads();
    }
    int excl = buf[threadIdx.x] - v + bsums[blockIdx.x];
    if (i < n) row_ptr[i] = excl;
    if (i == n - 1) row_ptr[n] = excl + v;
}

__global__ void csr_fill(const int* __restrict__ ei, int E,
                         const unsigned int* __restrict__ flags,
                         int cntoff, int srcbase,
                         int* __restrict__ cursor, int* __restrict__ edge_src) {
    bool is64 = (flags[0] == 0u);
    int e = blockIdx.x * blockDim.x + threadIdx.x;
    if (e >= E) return;
    int src, dst;
    if (is64) { src = ei[2 * e]; dst = ei[2 * E + 2 * e]; }
    else      { src = ei[e];     dst = ei[E + e]; }
    int pos = atomicAdd(&cursor[cntoff + dst], 1);
    edge_src[pos] = srcbase + src;
}

// ---------- gather-mean: half-wave (32 lanes) per dst row, bf16 x ----------
__global__ void gather_mean(const __hip_bfloat16* __restrict__ x,
                            const int* __restrict__ edge_src,
                            const int* __restrict__ row_ptr,
                            __hip_bfloat16* __restrict__ agg, int nrows) {
    int w = blockIdx.x * 8 + (threadIdx.x >> 5);   // 8 rows per 256-thread block
    int lane = threadIdx.x & 31;                   // feature pair index
    if (w >= nrows) return;
    int s = row_ptr[w], t = row_ptr[w + 1];
    const unsigned* xu = (const unsigned*)x;
    float a0 = 0.f, a1 = 0.f;
    int e = s;
    for (; e + 4 <= t; e += 4) {
        int s0 = edge_src[e], s1 = edge_src[e + 1], s2 = edge_src[e + 2], s3 = edge_src[e + 3];
        unsigned v0 = xu[(long)s0 * 32 + lane];
        unsigned v1 = xu[(long)s1 * 32 + lane];
        unsigned v2 = xu[(long)s2 * 32 + lane];
        unsigned v3 = xu[(long)s3 * 32 + lane];
        a0 += (blo(v0) + blo(v1)) + (blo(v2) + blo(v3));
        a1 += (bhi(v0) + bhi(v1)) + (bhi(v2) + bhi(v3));
    }
    for (; e < t; ++e) {
        unsigned v = xu[(long)edge_src[e] * 32 + lane];
        a0 += blo(v); a1 += bhi(v);
    }
    float inv = (t > s) ? 1.0f / (float)(t - s) : 0.f;
    __hip_bfloat162 o;
    o.x = __float2bfloat16(a0 * inv);
    o.y = __float2bfloat16(a1 * inv);
    ((__hip_bfloat162*)agg)[(long)w * 32 + lane] = o;
}

// ---------- fused per-dst-type layer update, MFMA (in place on x) ----------
// x[d,:] = relu( sum_p agg_p[d,:] @ Wl_p  +  x[d,:] @ Wsum  +  blsum )
// 64 rows x 64 cols per block; R+1 K=64 passes; mfma_f32_16x16x32_bf16.
__global__ __launch_bounds__(256) void fused_update_mfma(
    __hip_bfloat16* __restrict__ x,            // base of this dst type's rows
    const __hip_bfloat16* __restrict__ agg,    // concatenated agg base
    long aggRow0, long aggRow1, long aggRow2,  // agg row offsets per relation
    const bf16_t* __restrict__ wt,             // prepped WT buffer (4096 el per slot)
    int wtI0, int wtI1, int wtI2, int wtISelf, // slot ids: R agg passes + self
    int R,
    const float* __restrict__ blsum, int n_dst) {
    __shared__ bf16_t WTs[64 * 72];   // 9.2 KB, stride-72 pad (2-way bank alias = free)
    __shared__ bf16_t AS[64 * 72];    // 9.2 KB
    int t = threadIdx.x;
    int d0 = blockIdx.x * 64;
    int wv = t >> 6, lane = t & 63;
    int quad = lane >> 4, l16 = lane & 15;
    f32x4 acc[4] = {};
    long aggRows[3] = {aggRow0, aggRow1, aggRow2};
    int wtIdx[4] = {wtI0, wtI1, wtI2, wtISelf};

    for (int p = 0; p <= R; ++p) {
        const uint2* wsrc = (const uint2*)(wt + (long)wtIdx[p == R ? 3 : p] * 4096);
        const uint2* asrc = (p == R)
            ? (const uint2*)((const bf16_t*)x + (long)d0 * 64)
            : (const uint2*)((const bf16_t*)agg + (aggRows[p] + d0) * 64);
        #pragma unroll
        for (int i0 = 0; i0 < 4; ++i0) {
            int i = i0 * 256 + t;                 // 1024 uint2 = 4096 bf16
            int row = i >> 4, c = (i & 15) << 2;
            *(uint2*)&WTs[row * 72 + c] = wsrc[i];
            uint2 v = make_uint2(0u, 0u);
            if (d0 + row < n_dst) v = asrc[i];
            *(uint2*)&AS[row * 72 + c] = v;
        }
        __syncthreads();
        #pragma unroll
        for (int kc = 0; kc < 2; ++kc) {
            bf16x8 a = *(const bf16x8*)&AS[(wv * 16 + l16) * 72 + kc * 32 + quad * 8];
            #pragma unroll
            for (int nt = 0; nt < 4; ++nt) {
                bf16x8 b = *(const bf16x8*)&WTs[(nt * 16 + l16) * 72 + kc * 32 + quad * 8];
                acc[nt] = __builtin_amdgcn_mfma_f32_16x16x32_bf16(a, b, acc[nt], 0, 0, 0);
            }
        }
        __syncthreads();
    }

    #pragma unroll
    for (int nt = 0; nt < 4; ++nt) {
        int col = nt * 16 + l16;
        float bv = blsum[col];
        #pragma unroll
        for (int reg = 0; reg < 4; ++reg) {
            int dd = d0 + wv * 16 + quad * 4 + reg;
            if (dd < n_dst)
                x[(long)dd * 64 + col] = __float2bfloat16(fmaxf(acc[nt][reg] + bv, 0.f));
        }
    }
}

// ---------- head: softplus(x@projW+projb) @ outW + outb ----------
__global__ __launch_bounds__(256) void head_k(
    const __hip_bfloat16* __restrict__ xc,
    const void* __restrict__ projW, const void* __restrict__ projb,
    const void* __restrict__ outW, const void* __restrict__ outb,
    void* __restrict__ out, const unsigned int* __restrict__ flags, int n) {
    __shared__ float PW[64 * 64];
    __shared__ float PB[64], OW[64];
    __shared__ float ROW[4][64];
    bool wf32 = flags[2] > 64;
    bool of32 = flags[1] > 64;
    int t = threadIdx.x;
    for (int i = t; i < 4096; i += 256) PW[i] = wload(projW, i, wf32);
    if (t < 64) { PB[t] = wload(projb, t, wf32); OW[t] = wload(outW, t, wf32); }
    int wid = t >> 6, lane = t & 63;
    int d = blockIdx.x * 4 + wid;
    ROW[wid][lane] = (d < n) ? __bfloat162float(xc[(long)d * H64 + lane]) : 0.f;
    __syncthreads();
    if (d < n) {
        float s = PB[lane];
        #pragma unroll 8
        for (int k = 0; k < 64; ++k) s += ROW[wid][k] * PW[k * 64 + lane];
        float sp = fmaxf(s, 0.f) + log1pf(expf(-fabsf(s)));
        float c = sp * OW[lane];
        #pragma unroll
        for (int off = 32; off; off >>= 1) c += __shfl_down(c, off, 64);
        if (lane == 0) {
            float rv = c + wload(outb, 0, wf32);
            if (of32) ((float*)out)[d] = rv;
            else ((__hip_bfloat16*)out)[d] = __float2bfloat16(rv);
        }
    }
}

extern "C" void kernel_launch(void* const* d_in, const int* in_sizes, int n_in,
                              void* d_out, int out_size, void* d_ws, size_t ws_size,
                              hipStream_t stream) {
    static const int rel_st[9] = {0, 0, 0, 1, 1, 2, 0, 1, 2};
    static const int rel_dt[9] = {0, 1, 2, 1, 2, 2, 3, 3, 3};
    static const int relsOf[4][3] = {{0, -1, -1}, {1, 3, -1}, {2, 4, 5}, {6, 7, 8}};
    static const int Rof[4] = {1, 2, 3, 3};

    long rows[4], rowoff[4], total = 0;
    for (int t = 0; t < 4; ++t) { rows[t] = in_sizes[t] / H64; rowoff[t] = total; total += rows[t]; }
    long NX = total * H64;
    long Es[9], ET = 0;
    for (int r = 0; r < 9; ++r) { Es[r] = (long)in_sizes[11 + r] / 2; ET += Es[r]; }
    long cntoff[9], cntN = 0;
    for (int r = 0; r < 9; ++r) { cntoff[r] = cntN; cntN += rows[rel_dt[r]]; }
    long nb1 = (cntN + 255) / 256;

    unsigned int* flags = (unsigned int*)d_ws;
    char* wsbase = (char*)d_ws + 64;
    auto align16 = [](size_t v) { return (v + 15) & ~(size_t)15; };
    size_t off = 0;
    __hip_bfloat16* x = (__hip_bfloat16*)(wsbase + off);   off = align16(off + (size_t)NX * 2);
    __hip_bfloat16* agg = (__hip_bfloat16*)(wsbase + off); off = align16(off + (size_t)cntN * H64 * 2);
    int* cnt_i = (int*)(wsbase + off);                     off = align16(off + (size_t)cntN * 4);
    int* row_ptr = (int*)(wsbase + off);                   off = align16(off + (size_t)(cntN + 1) * 4);
    int* cursor = (int*)(wsbase + off);                    off = align16(off + (size_t)cntN * 4);
    int* edge_src = (int*)(wsbase + off);                  off = align16(off + (size_t)ET * 4);
    int* bsums = (int*)(wsbase + off);                     off = align16(off + (size_t)nb1 * 4);
    bf16_t* wt = (bf16_t*)(wsbase + off);                  off = align16(off + (size_t)39 * 4096 * 2);
    float* blsum = (float*)(wsbase + off);                 off = align16(off + (size_t)12 * 64 * 4);

    // format detection
    hipMemsetAsync(d_ws, 0, 64, stream);
    int nwords = 16384;
    if (in_sizes[11] < nwords) nwords = in_sizes[11];
    detect_k<<<1, 256, 0, stream>>>((const unsigned int*)d_in[11], nwords,
                                    (const unsigned short*)d_in[0],
                                    (const unsigned short*)d_in[4], flags);

    // x inputs -> bf16 ws
    for (int t = 0; t < 4; ++t) {
        long n = rows[t] * H64;
        int blocks = (int)((n + 255) / 256); if (blocks > 8192) blocks = 8192;
        conv_in<<<blocks, 256, 0, stream>>>(d_in[t], x + rowoff[t] * H64, n, flags);
    }

    // weight prep (transpose + pre-sum, bf16)
    prep_w<<<39, 256, 0, stream>>>(d_in[4], d_in[6], d_in[5], flags, wt, blsum);

    // CSR build (edge structure is layer-invariant)
    hipMemsetAsync(cnt_i, 0, (size_t)cntN * 4, stream);
    for (int r = 0; r < 9; ++r)
        if (Es[r] > 0)
            scatter_cnt_i<<<(int)((Es[r] + 255) / 256), 256, 0, stream>>>(
                (const int*)d_in[11 + r], (int)Es[r], flags, cnt_i + cntoff[r]);
    scan_bsum<<<(int)nb1, 256, 0, stream>>>(cnt_i, (int)cntN, bsums);
    scan_excl_single<<<1, 1024, 0, stream>>>(bsums, (int)nb1);
    scan_rowptr<<<(int)nb1, 256, 0, stream>>>(cnt_i, bsums, (int)cntN, row_ptr);
    hipMemcpyAsync(cursor, row_ptr, (size_t)cntN * 4, hipMemcpyDeviceToDevice, stream);
    for (int r = 0; r < 9; ++r)
        if (Es[r] > 0)
            csr_fill<<<(int)((Es[r] + 255) / 256), 256, 0, stream>>>(
                (const int*)d_in[11 + r], (int)Es[r], flags,
                (int)cntoff[r], (int)rowoff[rel_st[r]], cursor, edge_src);

    // layers
    for (int l = 0; l < 3; ++l) {
        gather_mean<<<(int)((cntN + 7) / 8), 256, 0, stream>>>(
            x, edge_src, row_ptr, agg, (int)cntN);
        for (int dt = 0; dt < 4; ++dt) {
            int R = Rof[dt];
            long ar[3] = {0, 0, 0};
            int wi[3] = {0, 0, 0};
            for (int p = 0; p < R; ++p) {
                int rr = relsOf[dt][p];
                ar[p] = cntoff[rr];
                wi[p] = l * 13 + rr;
            }
            long nd = rows[dt];
            fused_update_mfma<<<(int)((nd + 63) / 64), 256, 0, stream>>>(
                x + rowoff[dt] * H64, agg, ar[0], ar[1], ar[2],
                wt, wi[0], wi[1], wi[2], l * 13 + 9 + dt, R,
                blsum + (size_t)(l * 4 + dt) * 64, (int)nd);
        }
    }

    head_k<<<(int)((rows[3] + 3) / 4), 256, 0, stream>>>(
        x + rowoff[3] * H64, d_in[7], d_in[8], d_in[9], d_in[10], d_out, flags, (int)rows[3]);
}

// Round 5
// 1040.183 us; speedup vs baseline: 3.3804x; 1.0593x over previous
//
#include <hip/hip_runtime.h>
#include <hip/hip_bf16.h>

#define H64 64

typedef __bf16 bf16_t;
typedef __bf16 bf16x8 __attribute__((ext_vector_type(8)));
typedef float f32x4 __attribute__((ext_vector_type(4)));

// ---------- helpers ----------
__device__ __forceinline__ float wload(const void* p, long i, bool f32) {
    return f32 ? ((const float*)p)[i]
               : __bfloat162float(((const __hip_bfloat16*)p)[i]);
}
__device__ __forceinline__ float blo(unsigned v) { return __uint_as_float(v << 16); }
__device__ __forceinline__ float bhi(unsigned v) { return __uint_as_float(v & 0xffff0000u); }

// ---------- runtime format detection ----------
// flags[0] != 0 -> edge indices int32 (odd words nonzero); ==0 -> int64
// flags[1] > 64 -> x tensors f32; else bf16.  flags[2] > 64 -> weights f32.
__global__ void detect_k(const unsigned int* __restrict__ eiw, int nwords,
                         const unsigned short* __restrict__ xw,
                         const unsigned short* __restrict__ ww,
                         unsigned int* __restrict__ flags) {
    int t = threadIdx.x;
    unsigned int acc = 0;
    for (int i = 1 + 2 * t; i < nwords; i += 512) acc |= eiw[i];
    if (acc) atomicOr(&flags[0], acc);
    unsigned int cx = 0, cw = 0;
    for (int i = t; i < 8192; i += 256) {
        unsigned short w = xw[i];
        unsigned int e = (w >> 7) & 0xFF;
        if ((w & 0x7FFF) && (e == 0xFF || e < 0x40)) cx++;
        w = ww[i];
        e = (w >> 7) & 0xFF;
        if ((w & 0x7FFF) && (e == 0xFF || e < 0x40)) cw++;
    }
    if (cx) atomicAdd(&flags[1], cx);
    if (cw) atomicAdd(&flags[2], cw);
}

// ---------- convert harness x input -> bf16 ws storage ----------
__global__ void conv_in(const void* __restrict__ src, __hip_bfloat16* __restrict__ dst,
                        long n, const unsigned int* __restrict__ flags) {
    bool xf32 = flags[1] > 64;
    long i = (long)blockIdx.x * blockDim.x + threadIdx.x;
    long stride = (long)gridDim.x * blockDim.x;
    for (; i < n; i += stride) {
        float v = xf32 ? ((const float*)src)[i]
                       : __bfloat162float(((const __hip_bfloat16*)src)[i]);
        dst[i] = __float2bfloat16(v);
    }
}

// ---------- weight prep: bf16, transposed WT[n][k]; Wr pre-summed per (l,dt) ----------
// blockIdx.x = l*13 + p.  p<9: WT of Wl[l,p].  p in 9..12: dt=p-9, WT of sum(Wr) + blsum.
__global__ void prep_w(const void* __restrict__ Wl, const void* __restrict__ Wr,
                       const void* __restrict__ bl, const unsigned int* __restrict__ flags,
                       bf16_t* __restrict__ wt, float* __restrict__ blsum) {
    const int rel_dt[9] = {0, 1, 2, 1, 2, 2, 3, 3, 3};
    bool wf32 = flags[2] > 64;
    int l = blockIdx.x / 13, p = blockIdx.x % 13;
    bf16_t* dst = wt + (long)blockIdx.x * 4096;
    for (int i = threadIdx.x; i < 4096; i += 256) {
        int n = i >> 6, k = i & 63;
        float v;
        if (p < 9) {
            v = wload(Wl, (long)(l * 9 + p) * 4096 + k * 64 + n, wf32);
        } else {
            int dt = p - 9;
            v = 0.f;
            for (int r = 0; r < 9; ++r)
                if (rel_dt[r] == dt) v += wload(Wr, (long)(l * 9 + r) * 4096 + k * 64 + n, wf32);
        }
        __hip_bfloat16 h = __float2bfloat16(v);
        dst[i] = *(bf16_t*)&h;
    }
    if (p >= 9 && threadIdx.x < 64) {
        int dt = p - 9;
        float s = 0.f;
        for (int r = 0; r < 9; ++r)
            if (rel_dt[r] == dt) s += wload(bl, (long)(l * 9 + r) * 64 + threadIdx.x, wf32);
        blsum[(l * 4 + dt) * 64 + threadIdx.x] = s;
    }
}

// ---------- consolidated CSR build ----------
struct EdgeArgs {
    const int* ei[9];
    long eoff[10];    // cumulative edge counts
    int cntoff[9];    // concat row offset per relation
    int srcbase[9];   // global row base of src type
};

__global__ void count_all(EdgeArgs ea, const unsigned int* __restrict__ flags,
                          int* __restrict__ cnt) {
    long e = (long)blockIdx.x * 256 + threadIdx.x;
    if (e >= ea.eoff[9]) return;
    int r = 0;
    while (r < 8 && e >= ea.eoff[r + 1]) ++r;
    long el = e - ea.eoff[r];
    long E = ea.eoff[r + 1] - ea.eoff[r];
    bool is64 = (flags[0] == 0u);
    const int* ei = ea.ei[r];
    int dst = is64 ? ei[2 * E + 2 * el] : ei[E + el];
    atomicAdd(&cnt[ea.cntoff[r] + dst], 1);
}

__global__ void fill_all(EdgeArgs ea, const unsigned int* __restrict__ flags,
                         int* __restrict__ cursor, int* __restrict__ edge_src) {
    long e = (long)blockIdx.x * 256 + threadIdx.x;
    if (e >= ea.eoff[9]) return;
    int r = 0;
    while (r < 8 && e >= ea.eoff[r + 1]) ++r;
    long el = e - ea.eoff[r];
    long E = ea.eoff[r + 1] - ea.eoff[r];
    bool is64 = (flags[0] == 0u);
    const int* ei = ea.ei[r];
    int src, dst;
    if (is64) { src = ei[2 * el]; dst = ei[2 * E + 2 * el]; }
    else      { src = ei[el];     dst = ei[E + el]; }
    int pos = atomicAdd(&cursor[ea.cntoff[r] + dst], 1);
    edge_src[pos] = ea.srcbase[r] + src;
}

__global__ void scan_bsum(const int* __restrict__ cnt, int n, int* __restrict__ bsums) {
    __shared__ int red[256];
    int i = blockIdx.x * 256 + threadIdx.x;
    red[threadIdx.x] = (i < n) ? cnt[i] : 0;
    __syncthreads();
    for (int s = 128; s; s >>= 1) {
        if (threadIdx.x < s) red[threadIdx.x] += red[threadIdx.x + s];
        __syncthreads();
    }
    if (threadIdx.x == 0) bsums[blockIdx.x] = red[0];
}

__global__ void scan_excl_single(int* __restrict__ data, int n) {
    __shared__ int buf[1024];
    __shared__ int carry_s;
    if (threadIdx.x == 0) carry_s = 0;
    __syncthreads();
    for (int base = 0; base < n; base += 1024) {
        int i = base + threadIdx.x;
        int v = (i < n) ? data[i] : 0;
        buf[threadIdx.x] = v;
        __syncthreads();
        for (int off = 1; off < 1024; off <<= 1) {
            int tv = (threadIdx.x >= off) ? buf[threadIdx.x - off] : 0;
            __syncthreads();
            buf[threadIdx.x] += tv;
            __syncthreads();
        }
        int incl = buf[threadIdx.x];
        int carry = carry_s;
        if (i < n) data[i] = carry + incl - v;
        __syncthreads();
        if (threadIdx.x == 1023) carry_s = carry + buf[1023];
        __syncthreads();
    }
}

__global__ void scan_rowptr(const int* __restrict__ cnt, const int* __restrict__ bsums,
                            int n, int* __restrict__ row_ptr) {
    __shared__ int buf[256];
    int i = blockIdx.x * 256 + threadIdx.x;
    int v = (i < n) ? cnt[i] : 0;
    buf[threadIdx.x] = v;
    __syncthreads();
    for (int off = 1; off < 256; off <<= 1) {
        int tv = (threadIdx.x >= off) ? buf[threadIdx.x - off] : 0;
        __syncthreads();
        buf[threadIdx.x] += tv;
        __syncthreads();
    }
    int excl = buf[threadIdx.x] - v + bsums[blockIdx.x];
    if (i < n) row_ptr[i] = excl;
    if (i == n - 1) row_ptr[n] = excl + v;
}

// ---------- fused layer: gather-mean (into LDS) + MFMA update, all dst types ----------
struct LayerArgs {
    long rpOff[4][3];   // row_ptr offset per (dt, relation pass)
    int wtSlot[4][4];   // weight slot per (dt, pass); [3] = self
    long dstBase[4];    // global row base of dt
    int nDst[4];
    int Rdt[4];
    int blsumOff[4];
    int dtMap[4];       // dispatch-slot -> dt (longest first)
    int blockBase[5];   // block range per dispatch slot
};

__global__ __launch_bounds__(256) void fused_layer(
    const __hip_bfloat16* __restrict__ xold,   // concat base (read)
    __hip_bfloat16* __restrict__ xnew,         // concat base (write)
    const int* __restrict__ row_ptr,
    const int* __restrict__ edge_src,
    const bf16_t* __restrict__ wt,
    const float* __restrict__ blsum,
    LayerArgs la) {
    __shared__ bf16_t WTs[64 * 72];   // 9.2 KB (stride-72: 2-way bank alias = free)
    __shared__ bf16_t AS[64 * 72];    // 9.2 KB
    int bid = blockIdx.x;
    int slot = 0;
    while (slot < 3 && bid >= la.blockBase[slot + 1]) ++slot;
    int dt = la.dtMap[slot];
    int d0 = (bid - la.blockBase[slot]) * 64;
    int n_dst = la.nDst[dt];
    int R = la.Rdt[dt];
    long dbase = la.dstBase[dt];

    int t = threadIdx.x;
    int wv = t >> 6, lane = t & 63, quad = lane >> 4, l16 = lane & 15;
    int hw = t >> 5, hl = t & 31;
    const unsigned* xu = (const unsigned*)xold;
    f32x4 acc[4] = {};

    for (int p = 0; p <= R; ++p) {
        int ws = la.wtSlot[dt][p == R ? 3 : p];
        const uint2* wsrc = (const uint2*)(wt + (long)ws * 4096);
        #pragma unroll
        for (int i0 = 0; i0 < 4; ++i0) {
            int i = i0 * 256 + t;
            int row = i >> 4, c = (i & 15) << 2;
            *(uint2*)&WTs[row * 72 + c] = wsrc[i];
        }
        if (p < R) {
            // gather-mean: half-wave per dst row, 8 rows each
            const int* rp = row_ptr + la.rpOff[dt][p];
            for (int i = 0; i < 8; ++i) {
                int row = hw * 8 + i;
                int d = d0 + row;
                float a0 = 0.f, a1 = 0.f;
                int s = 0, tt = 0;
                if (d < n_dst) { s = rp[d]; tt = rp[d + 1]; }
                int e = s;
                for (; e + 4 <= tt; e += 4) {
                    int s0 = edge_src[e], s1 = edge_src[e + 1];
                    int s2 = edge_src[e + 2], s3 = edge_src[e + 3];
                    unsigned v0 = xu[(long)s0 * 32 + hl];
                    unsigned v1 = xu[(long)s1 * 32 + hl];
                    unsigned v2 = xu[(long)s2 * 32 + hl];
                    unsigned v3 = xu[(long)s3 * 32 + hl];
                    a0 += (blo(v0) + blo(v1)) + (blo(v2) + blo(v3));
                    a1 += (bhi(v0) + bhi(v1)) + (bhi(v2) + bhi(v3));
                }
                for (; e < tt; ++e) {
                    unsigned v = xu[(long)edge_src[e] * 32 + hl];
                    a0 += blo(v); a1 += bhi(v);
                }
                float inv = (tt > s) ? 1.f / (float)(tt - s) : 0.f;
                __hip_bfloat162 h;
                h.x = __float2bfloat16(a0 * inv);
                h.y = __float2bfloat16(a1 * inv);
                *(__hip_bfloat162*)&AS[row * 72 + hl * 2] = h;
            }
        } else {
            // self term: stage x rows
            const uint2* asrc = (const uint2*)((const char*)xold + (dbase + d0) * 128);
            #pragma unroll
            for (int i0 = 0; i0 < 4; ++i0) {
                int i = i0 * 256 + t;
                int row = i >> 4, c = (i & 15) << 2;
                uint2 v = make_uint2(0u, 0u);
                if (d0 + row < n_dst) v = asrc[i];
                *(uint2*)&AS[row * 72 + c] = v;
            }
        }
        __syncthreads();
        #pragma unroll
        for (int kc = 0; kc < 2; ++kc) {
            bf16x8 a = *(const bf16x8*)&AS[(wv * 16 + l16) * 72 + kc * 32 + quad * 8];
            #pragma unroll
            for (int nt = 0; nt < 4; ++nt) {
                bf16x8 b = *(const bf16x8*)&WTs[(nt * 16 + l16) * 72 + kc * 32 + quad * 8];
                acc[nt] = __builtin_amdgcn_mfma_f32_16x16x32_bf16(a, b, acc[nt], 0, 0, 0);
            }
        }
        __syncthreads();
    }

    const float* bs = blsum + la.blsumOff[dt];
    #pragma unroll
    for (int nt = 0; nt < 4; ++nt) {
        int col = nt * 16 + l16;
        float bv = bs[col];
        #pragma unroll
        for (int reg = 0; reg < 4; ++reg) {
            int dd = d0 + wv * 16 + quad * 4 + reg;
            if (dd < n_dst)
                xnew[(dbase + dd) * 64 + col] = __float2bfloat16(fmaxf(acc[nt][reg] + bv, 0.f));
        }
    }
}

// ---------- head: softplus(x@projW+projb) @ outW + outb ----------
__global__ __launch_bounds__(256) void head_k(
    const __hip_bfloat16* __restrict__ xc,
    const void* __restrict__ projW, const void* __restrict__ projb,
    const void* __restrict__ outW, const void* __restrict__ outb,
    void* __restrict__ out, const unsigned int* __restrict__ flags, int n) {
    __shared__ float PW[64 * 64];
    __shared__ float PB[64], OW[64];
    __shared__ float ROW[4][64];
    bool wf32 = flags[2] > 64;
    bool of32 = flags[1] > 64;
    int t = threadIdx.x;
    for (int i = t; i < 4096; i += 256) PW[i] = wload(projW, i, wf32);
    if (t < 64) { PB[t] = wload(projb, t, wf32); OW[t] = wload(outW, t, wf32); }
    int wid = t >> 6, lane = t & 63;
    int d = blockIdx.x * 4 + wid;
    ROW[wid][lane] = (d < n) ? __bfloat162float(xc[(long)d * H64 + lane]) : 0.f;
    __syncthreads();
    if (d < n) {
        float s = PB[lane];
        #pragma unroll 8
        for (int k = 0; k < 64; ++k) s += ROW[wid][k] * PW[k * 64 + lane];
        float sp = fmaxf(s, 0.f) + log1pf(expf(-fabsf(s)));
        float c = sp * OW[lane];
        #pragma unroll
        for (int off = 32; off; off >>= 1) c += __shfl_down(c, off, 64);
        if (lane == 0) {
            float rv = c + wload(outb, 0, wf32);
            if (of32) ((float*)out)[d] = rv;
            else ((__hip_bfloat16*)out)[d] = __float2bfloat16(rv);
        }
    }
}

extern "C" void kernel_launch(void* const* d_in, const int* in_sizes, int n_in,
                              void* d_out, int out_size, void* d_ws, size_t ws_size,
                              hipStream_t stream) {
    static const int rel_st[9] = {0, 0, 0, 1, 1, 2, 0, 1, 2};
    static const int rel_dt[9] = {0, 1, 2, 1, 2, 2, 3, 3, 3};
    static const int relsOf[4][3] = {{0, -1, -1}, {1, 3, -1}, {2, 4, 5}, {6, 7, 8}};
    static const int Rof[4] = {1, 2, 3, 3};

    long rows[4], rowoff[4], total = 0;
    for (int t = 0; t < 4; ++t) { rows[t] = in_sizes[t] / H64; rowoff[t] = total; total += rows[t]; }
    long NX = total * H64;
    long Es[9], ET = 0;
    for (int r = 0; r < 9; ++r) { Es[r] = (long)in_sizes[11 + r] / 2; ET += Es[r]; }
    long cntoff[9], cntN = 0;
    for (int r = 0; r < 9; ++r) { cntoff[r] = cntN; cntN += rows[rel_dt[r]]; }
    long nb1 = (cntN + 255) / 256;

    unsigned int* flags = (unsigned int*)d_ws;
    char* wsbase = (char*)d_ws + 64;
    auto align16 = [](size_t v) { return (v + 15) & ~(size_t)15; };
    size_t off = 0;
    __hip_bfloat16* xA = (__hip_bfloat16*)(wsbase + off); off = align16(off + (size_t)NX * 2);
    __hip_bfloat16* xB = (__hip_bfloat16*)(wsbase + off); off = align16(off + (size_t)NX * 2);
    int* cnt_i = (int*)(wsbase + off);                    off = align16(off + (size_t)cntN * 4);
    int* row_ptr = (int*)(wsbase + off);                  off = align16(off + (size_t)(cntN + 1) * 4);
    int* cursor = (int*)(wsbase + off);                   off = align16(off + (size_t)cntN * 4);
    int* edge_src = (int*)(wsbase + off);                 off = align16(off + (size_t)ET * 4);
    int* bsums = (int*)(wsbase + off);                    off = align16(off + (size_t)nb1 * 4);
    bf16_t* wt = (bf16_t*)(wsbase + off);                 off = align16(off + (size_t)39 * 4096 * 2);
    float* blsum = (float*)(wsbase + off);                off = align16(off + (size_t)12 * 64 * 4);

    // format detection
    hipMemsetAsync(d_ws, 0, 64, stream);
    int nwords = 16384;
    if (in_sizes[11] < nwords) nwords = in_sizes[11];
    detect_k<<<1, 256, 0, stream>>>((const unsigned int*)d_in[11], nwords,
                                    (const unsigned short*)d_in[0],
                                    (const unsigned short*)d_in[4], flags);

    // x inputs -> bf16 ws (xA)
    for (int t = 0; t < 4; ++t) {
        long n = rows[t] * H64;
        int blocks = (int)((n + 255) / 256); if (blocks > 8192) blocks = 8192;
        conv_in<<<blocks, 256, 0, stream>>>(d_in[t], xA + rowoff[t] * H64, n, flags);
    }

    // weight prep (transpose + pre-sum, bf16)
    prep_w<<<39, 256, 0, stream>>>(d_in[4], d_in[6], d_in[5], flags, wt, blsum);

    // CSR build (edge structure is layer-invariant)
    EdgeArgs ea;
    long ecum = 0;
    for (int r = 0; r < 9; ++r) {
        ea.ei[r] = (const int*)d_in[11 + r];
        ea.eoff[r] = ecum; ecum += Es[r];
        ea.cntoff[r] = (int)cntoff[r];
        ea.srcbase[r] = (int)rowoff[rel_st[r]];
    }
    ea.eoff[9] = ecum;

    hipMemsetAsync(cnt_i, 0, (size_t)cntN * 4, stream);
    count_all<<<(int)((ET + 255) / 256), 256, 0, stream>>>(ea, flags, cnt_i);
    scan_bsum<<<(int)nb1, 256, 0, stream>>>(cnt_i, (int)cntN, bsums);
    scan_excl_single<<<1, 1024, 0, stream>>>(bsums, (int)nb1);
    scan_rowptr<<<(int)nb1, 256, 0, stream>>>(cnt_i, bsums, (int)cntN, row_ptr);
    hipMemcpyAsync(cursor, row_ptr, (size_t)cntN * 4, hipMemcpyDeviceToDevice, stream);
    fill_all<<<(int)((ET + 255) / 256), 256, 0, stream>>>(ea, flags, cursor, edge_src);

    // fused layers (ping-pong xA -> xB -> xA -> xB)
    for (int l = 0; l < 3; ++l) {
        LayerArgs la;
        for (int dt = 0; dt < 4; ++dt) {
            la.nDst[dt] = (int)rows[dt];
            la.Rdt[dt] = Rof[dt];
            la.dstBase[dt] = rowoff[dt];
            la.blsumOff[dt] = (l * 4 + dt) * 64;
            for (int p = 0; p < 3; ++p) {
                int rr = (p < Rof[dt]) ? relsOf[dt][p] : relsOf[dt][0];
                la.rpOff[dt][p] = cntoff[rr];
                la.wtSlot[dt][p] = l * 13 + rr;
            }
            la.wtSlot[dt][3] = l * 13 + 9 + dt;
        }
        // dispatch order: cell first (longest blocks), then atom, bond, motif
        int order[4] = {3, 0, 1, 2};
        int bb = 0;
        for (int s = 0; s < 4; ++s) {
            la.dtMap[s] = order[s];
            la.blockBase[s] = bb;
            bb += (int)((rows[order[s]] + 63) / 64);
        }
        la.blockBase[4] = bb;

        const __hip_bfloat16* xo = (l & 1) ? xB : xA;
        __hip_bfloat16* xn = (l & 1) ? xA : xB;
        fused_layer<<<bb, 256, 0, stream>>>(xo, xn, row_ptr, edge_src, wt, blsum, la);
    }

    // after l=0,1,2: final x is in xB
    head_k<<<(int)((rows[3] + 3) / 4), 256, 0, stream>>>(
        xB + rowoff[3] * H64, d_in[7], d_in[8], d_in[9], d_in[10], d_out, flags, (int)rows[3]);
}